// Round 6
// baseline (314.714 us; speedup 1.0000x reference)
//
#include <hip/hip_runtime.h>

#define TT 512
#define BB 1024
#define INV2PI 0.15915494309189535f
#define INV4PI 0.07957747154594767f

__device__ __forceinline__ float frcp(float x){ return __builtin_amdgcn_rcpf(x); }

// cos(2*pi*r): rr = r - rint(r) in [-0.5,0.5]; degree-12 even Taylor of
// cos(pi*(2rr)) -- max err ~1.0e-4 at |rr|=0.5. Pure FMA chain (no v_cos).
__device__ __forceinline__ float cospoly(float r){
  float rr = r - rintf(r);
  float s = rr*rr;
  float p = fmaf(s, 7.90306816f, -26.42623488f);
  p = fmaf(p, s, 60.24464128f);
  p = fmaf(p, s, -85.45681728f);
  p = fmaf(p, s, 64.93939408f);
  p = fmaf(p, s, -19.7392088f);
  p = fmaf(p, s, 1.0f);
  return p;
}

// tanh(y) odd degree-13 Taylor, |y|<=1 (err <=1.1e-3 at |y|=1, ~0 for |y|<=0.5)
__device__ __forceinline__ float tanh13(float y){
  float s = y*y;
  float p = fmaf(s, 0.00359213f, -0.00886324f);
  p = fmaf(p, s, 0.02186948f);
  p = fmaf(p, s, -0.05396825f);
  p = fmaf(p, s, 0.13333333f);
  p = fmaf(p, s, -0.33333333f);
  p = fmaf(p, s, 1.0f);
  return y*p;
}

// DPP helpers (float through int). ror:n => lane l reads lane (l+16-n)%16.
#define DPPZ(v, ctrl) __int_as_float(__builtin_amdgcn_update_dpp(0, __float_as_int(v), (ctrl), 0xF, 0xF, true))
#define DPPR(v, ctrl) __int_as_float(__builtin_amdgcn_update_dpp(__float_as_int(v), __float_as_int(v), (ctrl), 0xF, 0xF, false))

// ---------------- Phase 1: xpre projection (pre-scaled to revolutions) ----
// xpre[t][b][c], c in [0,40):
//   c<32  (gate g=c>>3, jj=c&7):  (x@Wg[:64] + bg + thg) * INV2PI
//   c>=32 (kernel, jj=c-32):      (x@Wi2k + bi2k - bh2k) * INV4PI
// 8 rows x 20 cols per thread: weight ds_read stream amortized over 8 rows.
__global__ __launch_bounds__(256,1) void qlstm_proj(
    const float* __restrict__ x,
    const float* __restrict__ Wf, const float* __restrict__ bf, const float* __restrict__ thf,
    const float* __restrict__ Wi, const float* __restrict__ bi, const float* __restrict__ thi,
    const float* __restrict__ Wu, const float* __restrict__ bu, const float* __restrict__ thu,
    const float* __restrict__ Wo, const float* __restrict__ bo, const float* __restrict__ tho,
    const float* __restrict__ bh2k,
    const float* __restrict__ Wi2k, const float* __restrict__ bi2k,
    float* __restrict__ buf)
{
  __shared__ float4 wl4[64][10];
  __shared__ float bias[40];
  int tid = threadIdx.x;
  float* wl = (float*)wl4;
  for (int idx = tid; idx < 64*40; idx += 256){
    int d = idx / 40, c = idx - d*40;
    float v;
    if (c < 32){
      int g = c >> 3, jj = c & 7;
      const float* W = (g==0)?Wf:((g==1)?Wi:((g==2)?Wu:Wo));
      v = W[d*8+jj] * INV2PI;
    } else {
      v = Wi2k[d*8 + (c-32)] * INV4PI;
    }
    wl[d*40+c] = v;
  }
  if (tid < 40){
    int c = tid; float v;
    if (c < 32){
      int g = c >> 3, jj = c & 7;
      const float* bp = (g==0)?bf:((g==1)?bi:((g==2)?bu:bo));
      const float* tp = (g==0)?thf:((g==1)?thi:((g==2)?thu:tho));
      v = (bp[jj] + tp[jj]) * INV2PI;
    } else {
      v = (bi2k[c-32] - bh2k[c-32]) * INV4PI;
    }
    bias[c] = v;
  }
  __syncthreads();

  int ch = tid >> 7;               // column half (wave-uniform)
  int rt = tid & 127;
  long r0 = (long)blockIdx.x*1024 + (long)rt*8;   // 8 consecutive rows
  const float4* xp = (const float4*)(x + r0*64);
  int qb = ch*5;

  float4 acc[8][5];
#pragma unroll
  for (int r=0;r<8;++r)
#pragma unroll
    for (int q=0;q<5;++q){
      int c4 = (qb+q)*4;
      acc[r][q] = make_float4(bias[c4],bias[c4+1],bias[c4+2],bias[c4+3]);
    }

#pragma unroll 1
  for (int d4=0; d4<16; ++d4){
    float4 xv[8];
#pragma unroll
    for (int r=0;r<8;++r) xv[r] = xp[r*16 + d4];
#pragma unroll
    for (int dd=0; dd<4; ++dd){
#pragma unroll
      for (int q=0;q<5;++q){
        float4 wv = wl4[d4*4+dd][qb+q];
#pragma unroll
        for (int r=0;r<8;++r){
          float sc = (dd==0)?xv[r].x:((dd==1)?xv[r].y:((dd==2)?xv[r].z:xv[r].w));
          acc[r][q].x += sc*wv.x; acc[r][q].y += sc*wv.y;
          acc[r][q].z += sc*wv.z; acc[r][q].w += sc*wv.w;
        }
      }
    }
  }

#pragma unroll
  for (int r=0;r<8;++r){
    float4* ob = (float4*)(buf + (r0+r)*40 + qb*4);
#pragma unroll
    for (int q=0;q<5;++q) ob[q] = acc[r][q];
  }
}

// ---------------- Phase 2: scan, 16 lanes per batch element ----------------
// lane bits: j = bits0-2 (hidden unit), p = bit3 (gate pair: p=0 -> {f,i},
// p=1 -> {u,o}), element-in-wave = bits4-5. All cross-lane via DPP.
// Activations all-polynomial; single rcp on the chain (Pade(5,4) tanh(c)).
__global__ __launch_bounds__(64) void qlstm_scan(
    const float* __restrict__ buf,
    const float* __restrict__ Wf, const float* __restrict__ Wi,
    const float* __restrict__ Wu, const float* __restrict__ Wo,
    const float* __restrict__ Wh2k,
    float* __restrict__ out,
    float* __restrict__ hstate, float* __restrict__ cstate,
    int t0, int tc, int initf, int lastf)
{
  int tid = threadIdx.x;          // 64
  int j = tid & 7;
  bool pb = (tid & 8) != 0;       // gate-pair select
  bool j4 = (j & 4) != 0;
  int b = blockIdx.x*4 + (tid >> 4);

  // slot A: p=0 -> f (sigmoid), p=1 -> u (tanh) ; slot B: i / o (sigmoid)
  const float* WA = pb ? Wu : Wf;
  const float* WB = pb ? Wo : Wi;
  float wrA[8], wrB[8], wkr[8];
#pragma unroll
  for (int s=0;s<8;++s){
    int k = (j + s) & 7;
    wrA[s] = WA[(64+k)*8 + j] * INV2PI;
    wrB[s] = WB[(64+k)*8 + j] * INV2PI;
    wkr[s] = Wh2k[k*8 + j] * INV4PI;
  }
  // tanh-core pre/post constants: sigmoid(x)=0.5+0.5*tanh(x/2); tanh(x)=tanh(x)
  float preY  = pb ? 1.0f : 0.5f;
  float postM = pb ? 1.0f : 0.5f;
  float postB = pb ? 0.0f : 0.5f;

  float h, c;
  if (initf){ h = 0.f; c = 0.f; }
  else { h = hstate[b*8+j]; c = cstate[b*8+j]; }

  const int S = BB*40;            // per-step stride (floats)
  int oA = b*40 + (pb?16:0) + j;  // gate A pre offset (floats)
  int oK = b*40 + 32 + j;         // kernel pre offset

  float xAq[4], xBq[4], xKq[4];
#pragma unroll
  for (int i=0;i<4;++i){
    xAq[i]=buf[oA + i*S]; xBq[i]=buf[oA + 8 + i*S]; xKq[i]=buf[oK + i*S];
  }
  int offA = oA + 4*S;            // prefetch cursor (row tt+4)
  int offK = oK + 4*S;
  int osto = (t0*BB + b)*8 + j;   // output cursor

  bool st = !pb;
  for (int tt4 = 0; tt4 < tc; tt4 += 4){
#pragma unroll
    for (int u=0; u<4; ++u){
      int tt = tt4 + u;
      float xA = xAq[u], xB = xBq[u], xK = xKq[u];
      // branch-free clamped prefetch (duplicate last row when past end; unused)
      xAq[u] = buf[offA]; xBq[u] = buf[offA + 8]; xKq[u] = buf[offK];
      int inc = (tt + 5 < tc) ? S : 0;
      offA += inc; offK += inc;

      // independent rotations of h (rotate-left-by-s within 16-row)
      float hr1 = DPPR(h,0x12F), hr2 = DPPR(h,0x12E), hr3 = DPPR(h,0x12D),
            hr4 = DPPR(h,0x12C), hr5 = DPPR(h,0x12B), hr6 = DPPR(h,0x12A),
            hr7 = DPPR(h,0x129);
      // matvecs (pre-scaled weights), 2-accumulator trees
      float aA0 =        h*wrA[0];  aA0 = fmaf(hr2,wrA[2],aA0); aA0 = fmaf(hr4,wrA[4],aA0); aA0 = fmaf(hr6,wrA[6],aA0);
      float aA1 =      hr1*wrA[1];  aA1 = fmaf(hr3,wrA[3],aA1); aA1 = fmaf(hr5,wrA[5],aA1); aA1 = fmaf(hr7,wrA[7],aA1);
      float aA = aA0 + aA1;
      float aB0 =        h*wrB[0];  aB0 = fmaf(hr2,wrB[2],aB0); aB0 = fmaf(hr4,wrB[4],aB0); aB0 = fmaf(hr6,wrB[6],aB0);
      float aB1 =      hr1*wrB[1];  aB1 = fmaf(hr3,wrB[3],aB1); aB1 = fmaf(hr5,wrB[5],aB1); aB1 = fmaf(hr7,wrB[7],aB1);
      float aB = aB0 + aB1;
      float aK0 =        h*wkr[0];  aK0 = fmaf(hr2,wkr[2],aK0); aK0 = fmaf(hr4,wkr[4],aK0); aK0 = fmaf(hr6,wkr[6],aK0);
      float aK1 =      hr1*wkr[1];  aK1 = fmaf(hr3,wkr[3],aK1); aK1 = fmaf(hr5,wkr[5],aK1); aK1 = fmaf(hr7,wkr[7],aK1);
      float aK = aK0 + aK1;

      // kernel weight: |prod_j cos(2pi*(aK - xK))| over 8-lane j-group, all DPP
      float kv = cospoly(aK - xK);
      kv *= DPPR(kv,0xB1);                       // xor1 (quad_perm)
      kv *= DPPR(kv,0x4E);                       // xor2 (quad_perm)
      { float t4a = DPPR(kv,0x124), t4b = DPPR(kv,0x12C);  // xor4 via ror4/ror12
        kv *= (j4 ? t4a : t4b); }
      float wk = fabsf(kv);

      // per-slot qlayer: z = cos(2pi*(a + x)); gq = (j==0 ? prod z[1:] : cumprod z[0..j]) * wk
#define CUMQ(ZV, GQ) { \
      float zz = (ZV); \
      float pz = zz, s_; \
      s_ = DPPZ(pz,0x111); pz *= ((j>=1)? s_ : 1.0f); \
      s_ = DPPZ(pz,0x112); pz *= ((j>=2)? s_ : 1.0f); \
      s_ = DPPZ(pz,0x114); pz *= ((j>=4)? s_ : 1.0f); \
      float q = (j==0)? 1.0f : zz; \
      q *= DPPR(q,0xB1); \
      q *= DPPR(q,0x4E); \
      { float q4a = DPPR(q,0x124), q4b = DPPR(q,0x12C); q *= (j4 ? q4a : q4b); } \
      GQ = ((j==0)? q : pz) * wk; }

      float gA, gB;
      CUMQ(cospoly(aA + xA), gA)
      CUMQ(cospoly(aB + xB), gB)
#undef CUMQ

      // slot A: tanh-core, per-lane pre/post constants
      float tA = tanh13(gA * preY);
      float actA = fmaf(tA, postM, postB);
      // slot B: sigmoid via tanh-core
      float tB = tanh13(gB * 0.5f);
      float actB = fmaf(tB, 0.5f, 0.5f);

      // cross-pair gather via ror:8 (lane l <-> l^8)
      float gAo = DPPR(actA,0x128);
      float gBo = DPPR(actB,0x128);
      float fv = pb ? gAo  : actA;
      float uv = pb ? actA : gAo;
      float iv = pb ? gBo  : actB;
      float ov = pb ? actB : gBo;

      c = fmaf(fv, c, iv*uv);
      // tanh(c) via Pade(5,4): |c| <= ~2.1, err <= 3e-5 (one rcp on the chain)
      float c2 = c * c;
      float n1 = c2 + 105.0f;
      float num = fmaf(c2, n1, 945.0f);
      float d1 = fmaf(c2, 15.0f, 420.0f);
      float den = fmaf(c2, d1, 945.0f);
      float tch = c * num * frcp(den);
      h = ov * tch;

      if (st) out[osto] = h;
      osto += BB*8;
    }
  }

  if (st){
    if (lastf){
      out[(size_t)TT*BB*8 + (size_t)b*8 + j] = h;
      out[(size_t)TT*BB*8 + (size_t)BB*8 + (size_t)b*8 + j] = c;
    } else {
      hstate[b*8+j] = h;
      cstate[b*8+j] = c;
    }
  }
}

extern "C" void kernel_launch(void* const* d_in, const int* in_sizes, int n_in,
                              void* d_out, int out_size, void* d_ws, size_t ws_size,
                              hipStream_t stream)
{
  const float* x    = (const float*)d_in[0];
  const float* Wf   = (const float*)d_in[1];
  const float* bf   = (const float*)d_in[2];
  const float* thf  = (const float*)d_in[3];
  const float* Wi   = (const float*)d_in[4];
  const float* bi   = (const float*)d_in[5];
  const float* thi  = (const float*)d_in[6];
  const float* Wu   = (const float*)d_in[7];
  const float* bu   = (const float*)d_in[8];
  const float* thu  = (const float*)d_in[9];
  const float* Wo   = (const float*)d_in[10];
  const float* bo   = (const float*)d_in[11];
  const float* tho  = (const float*)d_in[12];
  const float* Wh2k = (const float*)d_in[13];
  const float* bh2k = (const float*)d_in[14];
  const float* Wi2k = (const float*)d_in[15];
  const float* bi2k = (const float*)d_in[16];
  float* out = (float*)d_out;

  // ws layout: hstate[8192 f] | cstate[8192 f] | xpre buf [tc][BB][40]
  float* hstate = (float*)d_ws;
  float* cstate = hstate + BB*8;
  float* buf    = cstate + BB*8;
  long long avail = (long long)ws_size - (long long)(2*BB*8*sizeof(float));
  const long long per_step = 40ll*BB*sizeof(float);  // 160 KiB per time step
  int tc = TT;
  while (tc > 4 && (long long)tc*per_step > avail) tc >>= 1;

  for (int t0 = 0; t0 < TT; t0 += tc){
    int cur = (TT - t0 < tc) ? (TT - t0) : tc;
    qlstm_proj<<<(cur*BB)/1024, 256, 0, stream>>>(
        x + (size_t)t0*BB*64,
        Wf,bf,thf, Wi,bi,thi, Wu,bu,thu, Wo,bo,tho,
        bh2k, Wi2k, bi2k, buf);
    qlstm_scan<<<BB/4, 64, 0, stream>>>(
        buf, Wf, Wi, Wu, Wo, Wh2k, out, hstate, cstate,
        t0, cur, (t0==0)?1:0, (t0+cur>=TT)?1:0);
  }
}

// Round 8
// 294.758 us; speedup vs baseline: 1.0677x; 1.0677x over previous
//
#include <hip/hip_runtime.h>

#define TT 512
#define BB 1024
#define INV2PI 0.15915494309189535f
#define INV4PI 0.07957747154594767f

__device__ __forceinline__ float frcp(float x){ return __builtin_amdgcn_rcpf(x); }
// cos(2*pi*r) with r in revolutions; exact fract reduction + V_COS
__device__ __forceinline__ float fcosrev(float r){
  float rr = r - floorf(r);
  return __builtin_amdgcn_cosf(rr);
}

// tanh(y) odd degree-13 Taylor, |y|<=1 (err <=1.1e-3 at |y|=1)
__device__ __forceinline__ float tanh13(float y){
  float s = y*y;
  float p = fmaf(s, 0.00359213f, -0.00886324f);
  p = fmaf(p, s, 0.02186948f);
  p = fmaf(p, s, -0.05396825f);
  p = fmaf(p, s, 0.13333333f);
  p = fmaf(p, s, -0.33333333f);
  p = fmaf(p, s, 1.0f);
  return y*p;
}

// DPP helpers (validated R3-R6).
#define DPPZ(v, ctrl) __int_as_float(__builtin_amdgcn_update_dpp(0, __float_as_int(v), (ctrl), 0xF, 0xF, true))
#define DPPR(v, ctrl) __int_as_float(__builtin_amdgcn_update_dpp(__float_as_int(v), __float_as_int(v), (ctrl), 0xF, 0xF, false))

// ---------------- Phase 1: xpre projection (pre-scaled to revolutions) ----
__global__ __launch_bounds__(256,1) void qlstm_proj(
    const float* __restrict__ x,
    const float* __restrict__ Wf, const float* __restrict__ bf, const float* __restrict__ thf,
    const float* __restrict__ Wi, const float* __restrict__ bi, const float* __restrict__ thi,
    const float* __restrict__ Wu, const float* __restrict__ bu, const float* __restrict__ thu,
    const float* __restrict__ Wo, const float* __restrict__ bo, const float* __restrict__ tho,
    const float* __restrict__ bh2k,
    const float* __restrict__ Wi2k, const float* __restrict__ bi2k,
    float* __restrict__ buf)
{
  __shared__ float4 wl4[64][10];
  __shared__ float bias[40];
  int tid = threadIdx.x;
  float* wl = (float*)wl4;
  for (int idx = tid; idx < 64*40; idx += 256){
    int d = idx / 40, c = idx - d*40;
    float v;
    if (c < 32){
      int g = c >> 3, jj = c & 7;
      const float* W = (g==0)?Wf:((g==1)?Wi:((g==2)?Wu:Wo));
      v = W[d*8+jj] * INV2PI;
    } else {
      v = Wi2k[d*8 + (c-32)] * INV4PI;
    }
    wl[d*40+c] = v;
  }
  if (tid < 40){
    int c = tid; float v;
    if (c < 32){
      int g = c >> 3, jj = c & 7;
      const float* bp = (g==0)?bf:((g==1)?bi:((g==2)?bu:bo));
      const float* tp = (g==0)?thf:((g==1)?thi:((g==2)?thu:tho));
      v = (bp[jj] + tp[jj]) * INV2PI;
    } else {
      v = (bi2k[c-32] - bh2k[c-32]) * INV4PI;
    }
    bias[c] = v;
  }
  __syncthreads();

  int ch = tid >> 7;               // column half (wave-uniform)
  int rt = tid & 127;
  long r0 = (long)blockIdx.x*1024 + (long)rt*8;   // 8 consecutive rows
  const float4* xp = (const float4*)(x + r0*64);
  int qb = ch*5;

  float4 acc[8][5];
#pragma unroll
  for (int r=0;r<8;++r)
#pragma unroll
    for (int q=0;q<5;++q){
      int c4 = (qb+q)*4;
      acc[r][q] = make_float4(bias[c4],bias[c4+1],bias[c4+2],bias[c4+3]);
    }

#pragma unroll 1
  for (int d4=0; d4<16; ++d4){
    float4 xv[8];
#pragma unroll
    for (int r=0;r<8;++r) xv[r] = xp[r*16 + d4];
#pragma unroll
    for (int dd=0; dd<4; ++dd){
#pragma unroll
      for (int q=0;q<5;++q){
        float4 wv = wl4[d4*4+dd][qb+q];
#pragma unroll
        for (int r=0;r<8;++r){
          float sc = (dd==0)?xv[r].x:((dd==1)?xv[r].y:((dd==2)?xv[r].z:xv[r].w));
          acc[r][q].x += sc*wv.x; acc[r][q].y += sc*wv.y;
          acc[r][q].z += sc*wv.z; acc[r][q].w += sc*wv.w;
        }
      }
    }
  }

#pragma unroll
  for (int r=0;r<8;++r){
    float4* ob = (float4*)(buf + (r0+r)*40 + qb*4);
#pragma unroll
    for (int q=0;q<5;++q) ob[q] = acc[r][q];
  }
}

// ---------------- Phase 2: scan, 16 lanes per batch element ----------------
// lane bits: j=bits0-2, p=bit3 (pair: 0->{f,i}, 1->{u,o}), elem=bits4-5.
// Weights pinned in named VGPRs (asm). launch_bounds(64,1): full VGPR budget.
// Cumprod uses masked DPPZ (masks ALSO guard the 8-group boundary at lane 8 --
// row_shr works on 16-lane rows; do NOT replace with old=1.0 bound_ctrl form).
__global__ __launch_bounds__(64,1) void qlstm_scan(
    const float* __restrict__ buf,
    const float* __restrict__ Wf, const float* __restrict__ Wi,
    const float* __restrict__ Wu, const float* __restrict__ Wo,
    const float* __restrict__ Wh2k,
    float* __restrict__ out,
    float* __restrict__ hstate, float* __restrict__ cstate,
    int t0, int tc, int initf, int lastf)
{
  int tid = threadIdx.x;          // 64
  int j = tid & 7;
  bool pb = (tid & 8) != 0;       // gate-pair select
  bool j4 = (j & 4) != 0;
  int b = blockIdx.x*4 + (tid >> 4);

  // slot A: p=0 -> f (sigmoid), p=1 -> u (tanh) ; slot B: i / o (sigmoid)
  const float* WA = pb ? Wu : Wf;
  const float* WB = pb ? Wo : Wi;
  // named weight registers (rotated layout: step s uses h[(j+s)&7])
#define LDW(S) \
  float wA##S = WA[(64+((j+S)&7))*8 + j] * INV2PI; \
  float wB##S = WB[(64+((j+S)&7))*8 + j] * INV2PI; \
  float wK##S = Wh2k[((j+S)&7)*8 + j] * INV4PI;
  LDW(0) LDW(1) LDW(2) LDW(3) LDW(4) LDW(5) LDW(6) LDW(7)
#undef LDW
  // pin all 24 weights into architectural VGPRs (non-rematerializable)
  asm volatile("" :
    "+v"(wA0),"+v"(wA1),"+v"(wA2),"+v"(wA3),"+v"(wA4),"+v"(wA5),"+v"(wA6),"+v"(wA7),
    "+v"(wB0),"+v"(wB1),"+v"(wB2),"+v"(wB3),"+v"(wB4),"+v"(wB5),"+v"(wB6),"+v"(wB7),
    "+v"(wK0),"+v"(wK1),"+v"(wK2),"+v"(wK3),"+v"(wK4),"+v"(wK5),"+v"(wK6),"+v"(wK7));

  // tanh-core constants: sigmoid(x)=0.5+0.5*tanh(x/2); tanh(x)=tanh(x)
  float preY  = pb ? 1.0f : 0.5f;
  float postM = pb ? 1.0f : 0.5f;
  float postB = pb ? 0.0f : 0.5f;

  float h, c;
  if (initf){ h = 0.f; c = 0.f; }
  else { h = hstate[b*8+j]; c = cstate[b*8+j]; }

  const int S = BB*40;            // per-step stride (floats)
  int oA = b*40 + (pb?16:0) + j;  // gate A pre offset (floats)
  int oK = b*40 + 32 + j;         // kernel pre offset

  float xAq[4], xBq[4], xKq[4];
#pragma unroll
  for (int i=0;i<4;++i){
    xAq[i]=buf[oA + i*S]; xBq[i]=buf[oA + 8 + i*S]; xKq[i]=buf[oK + i*S];
  }
  int offA = oA + 4*S;            // prefetch cursor (row tt+4)
  int offK = oK + 4*S;
  int osto = (t0*BB + b)*8 + j;   // output cursor

  bool st = !pb;
  for (int tt4 = 0; tt4 < tc; tt4 += 4){
#pragma unroll
    for (int u=0; u<4; ++u){
      int tt = tt4 + u;
      float xA = xAq[u], xB = xBq[u], xK = xKq[u];
      // branch-free clamped prefetch (duplicate last row when past end; unused)
      xAq[u] = buf[offA]; xBq[u] = buf[offA + 8]; xKq[u] = buf[offK];
      int inc = (tt + 5 < tc) ? S : 0;
      offA += inc; offK += inc;

      // independent rotations of h (rotate-left-by-s within 16-row)
      float hr1 = DPPR(h,0x12F), hr2 = DPPR(h,0x12E), hr3 = DPPR(h,0x12D),
            hr4 = DPPR(h,0x12C), hr5 = DPPR(h,0x12B), hr6 = DPPR(h,0x12A),
            hr7 = DPPR(h,0x129);
      // matvecs, 2-accumulator trees, pinned weights
      float aA0 =       h*wA0;  aA0 = fmaf(hr2,wA2,aA0); aA0 = fmaf(hr4,wA4,aA0); aA0 = fmaf(hr6,wA6,aA0);
      float aA1 =     hr1*wA1;  aA1 = fmaf(hr3,wA3,aA1); aA1 = fmaf(hr5,wA5,aA1); aA1 = fmaf(hr7,wA7,aA1);
      float aA = aA0 + aA1;
      float aB0 =       h*wB0;  aB0 = fmaf(hr2,wB2,aB0); aB0 = fmaf(hr4,wB4,aB0); aB0 = fmaf(hr6,wB6,aB0);
      float aB1 =     hr1*wB1;  aB1 = fmaf(hr3,wB3,aB1); aB1 = fmaf(hr5,wB5,aB1); aB1 = fmaf(hr7,wB7,aB1);
      float aB = aB0 + aB1;
      float aK0 =       h*wK0;  aK0 = fmaf(hr2,wK2,aK0); aK0 = fmaf(hr4,wK4,aK0); aK0 = fmaf(hr6,wK6,aK0);
      float aK1 =     hr1*wK1;  aK1 = fmaf(hr3,wK3,aK1); aK1 = fmaf(hr5,wK5,aK1); aK1 = fmaf(hr7,wK7,aK1);
      float aK = aK0 + aK1;

      // kernel weight: |prod_j cos(2pi*(aK - xK))| over 8-lane j-group (DPP)
      float kv = fcosrev(aK - xK);
      kv *= DPPR(kv,0xB1);                       // xor1 (quad_perm)
      kv *= DPPR(kv,0x4E);                       // xor2 (quad_perm)
      { float t4a = DPPR(kv,0x124), t4b = DPPR(kv,0x12C);  // xor4 via ror4/ror12
        kv *= (j4 ? t4a : t4b); }
      float wk = fabsf(kv);

      // per-slot qlayer: z=cos(2pi*(a+x)); gq=(j==0 ? prod z[1:] : cumprod z[0..j])*wk
      // masked cumprod: masks guard BOTH the 16-row edge and the lane-8 group edge
#define CUMQ(ZV, GQ) { \
      float zz = (ZV); \
      float pz = zz, s_; \
      s_ = DPPZ(pz,0x111); pz *= ((j>=1)? s_ : 1.0f); \
      s_ = DPPZ(pz,0x112); pz *= ((j>=2)? s_ : 1.0f); \
      s_ = DPPZ(pz,0x114); pz *= ((j>=4)? s_ : 1.0f); \
      float q = (j==0)? 1.0f : zz; \
      q *= DPPR(q,0xB1); \
      q *= DPPR(q,0x4E); \
      { float q4a = DPPR(q,0x124), q4b = DPPR(q,0x12C); q *= (j4 ? q4a : q4b); } \
      GQ = ((j==0)? q : pz) * wk; }

      float gA, gB;
      CUMQ(fcosrev(aA + xA), gA)
      CUMQ(fcosrev(aB + xB), gB)
#undef CUMQ

      // slot A: tanh-core with per-lane pre/post constants; slot B: sigmoid
      float tA = tanh13(gA * preY);
      float actA = fmaf(tA, postM, postB);
      float tB = tanh13(gB * 0.5f);
      float actB = fmaf(tB, 0.5f, 0.5f);

      // cross-pair gather via ror:8 (lane l <-> l^8)
      float gAo = DPPR(actA,0x128);
      float gBo = DPPR(actB,0x128);
      float fv = pb ? gAo  : actA;
      float uv = pb ? actA : gAo;
      float iv = pb ? gBo  : actB;
      float ov = pb ? actB : gBo;

      c = fmaf(fv, c, iv*uv);
      // tanh(c) via Pade(5,4): |c| <= ~2.1, err <= 3e-5 (one rcp on the chain)
      float c2 = c * c;
      float n1 = c2 + 105.0f;
      float num = fmaf(c2, n1, 945.0f);
      float d1 = fmaf(c2, 15.0f, 420.0f);
      float den = fmaf(c2, d1, 945.0f);
      float tch = c * num * frcp(den);
      h = ov * tch;

      if (st) out[osto] = h;
      osto += BB*8;
    }
  }

  if (st){
    if (lastf){
      out[(size_t)TT*BB*8 + (size_t)b*8 + j] = h;
      out[(size_t)TT*BB*8 + (size_t)BB*8 + (size_t)b*8 + j] = c;
    } else {
      hstate[b*8+j] = h;
      cstate[b*8+j] = c;
    }
  }
}

extern "C" void kernel_launch(void* const* d_in, const int* in_sizes, int n_in,
                              void* d_out, int out_size, void* d_ws, size_t ws_size,
                              hipStream_t stream)
{
  const float* x    = (const float*)d_in[0];
  const float* Wf   = (const float*)d_in[1];
  const float* bf   = (const float*)d_in[2];
  const float* thf  = (const float*)d_in[3];
  const float* Wi   = (const float*)d_in[4];
  const float* bi   = (const float*)d_in[5];
  const float* thi  = (const float*)d_in[6];
  const float* Wu   = (const float*)d_in[7];
  const float* bu   = (const float*)d_in[8];
  const float* thu  = (const float*)d_in[9];
  const float* Wo   = (const float*)d_in[10];
  const float* bo   = (const float*)d_in[11];
  const float* tho  = (const float*)d_in[12];
  const float* Wh2k = (const float*)d_in[13];
  const float* bh2k = (const float*)d_in[14];
  const float* Wi2k = (const float*)d_in[15];
  const float* bi2k = (const float*)d_in[16];
  float* out = (float*)d_out;

  // ws layout: hstate[8192 f] | cstate[8192 f] | xpre buf [tc][BB][40]
  float* hstate = (float*)d_ws;
  float* cstate = hstate + BB*8;
  float* buf    = cstate + BB*8;
  long long avail = (long long)ws_size - (long long)(2*BB*8*sizeof(float));
  const long long per_step = 40ll*BB*sizeof(float);  // 160 KiB per time step
  int tc = TT;
  while (tc > 4 && (long long)tc*per_step > avail) tc >>= 1;

  for (int t0 = 0; t0 < TT; t0 += tc){
    int cur = (TT - t0 < tc) ? (TT - t0) : tc;
    qlstm_proj<<<(cur*BB)/1024, 256, 0, stream>>>(
        x + (size_t)t0*BB*64,
        Wf,bf,thf, Wi,bi,thi, Wu,bu,thu, Wo,bo,tho,
        bh2k, Wi2k, bi2k, buf);
    qlstm_scan<<<BB/4, 64, 0, stream>>>(
        buf, Wf, Wi, Wu, Wo, Wh2k, out, hstate, cstate,
        t0, cur, (t0==0)?1:0, (t0+cur>=TT)?1:0);
  }
}